// Round 18
// baseline (345.054 us; speedup 1.0000x reference)
//
#include <hip/hip_runtime.h>
#include <hip/hip_cooperative_groups.h>
#include <cstdint>
#include <cstddef>

namespace cg = cooperative_groups;

// B=2 S=1024 H=4096 NH=32 NKV=8 HD=128 GROUPS=4
typedef short bf16x8 __attribute__((ext_vector_type(8)));
typedef float f32x4 __attribute__((ext_vector_type(4)));

__device__ __forceinline__ unsigned short f2bf(float f) {
  unsigned int u = __builtin_bit_cast(unsigned int, f);
  u += 0x7fffu + ((u >> 16) & 1u);
  return (unsigned short)(u >> 16);
}

// ---- transpose tile core: 64x64, float4 loads / bf16x8 stores ----
__device__ __forceinline__ void transpose_tile(const float* __restrict__ src,
                                               unsigned short* __restrict__ dst,
                                               int K, int N, int n0, int k0, int tid,
                                               float* __restrict__ tb /* [64][65] */) {
#pragma unroll
  for (int i = 0; i < 4; ++i) {
    const int lr = tid >> 4, lc = (tid & 15) * 4;
    float4 v = *(const float4*)(src + (size_t)(k0 + i * 16 + lr) * N + n0 + lc);
    tb[(i * 16 + lr) * 65 + lc] = v.x;
    tb[(i * 16 + lr) * 65 + lc + 1] = v.y;
    tb[(i * 16 + lr) * 65 + lc + 2] = v.z;
    tb[(i * 16 + lr) * 65 + lc + 3] = v.w;
  }
  __syncthreads();
  const int nr = tid >> 3, kk = (tid & 7) * 8;
#pragma unroll
  for (int i = 0; i < 2; ++i) {
    int n = nr + i * 32;
    bf16x8 v;
#pragma unroll
    for (int j = 0; j < 8; ++j) v[j] = (short)f2bf(tb[(kk + j) * 65 + n]);
    *(bf16x8*)(dst + (size_t)(n0 + n) * K + k0 + kk) = v;
  }
}

// ---- GEMM K-loop core (R11 proven: depth-1 reg-staged, XOR-swizzled ds_write) ----
__device__ __forceinline__ void gemm_core(const unsigned short* __restrict__ A,
                                          const unsigned short* __restrict__ Bt,
                                          int K, int bm, int bn, int tid,
                                          unsigned short* __restrict__ lA,
                                          unsigned short* __restrict__ lB,
                                          f32x4 (&acc)[4][4]) {
  const int lane = tid & 63, wv = tid >> 6;
  const int wr = wv >> 1, wc = wv & 1;
  const int l16 = lane & 15, lhi = lane >> 4;
  bf16x8 ar[4], br[4];
#pragma unroll
  for (int i = 0; i < 4; ++i) {
    int c = tid + i * 256, row = c >> 3, c16 = c & 7;
    ar[i] = *(const bf16x8*)(A + (size_t)(bm + row) * K + 0 + c16 * 8);
    br[i] = *(const bf16x8*)(Bt + (size_t)(bn + row) * K + 0 + c16 * 8);
  }
  const int nkt = K >> 6;
  for (int kt = 0; kt < nkt; ++kt) {
    __syncthreads();
#pragma unroll
    for (int i = 0; i < 4; ++i) {
      int c = tid + i * 256, row = c >> 3, c16 = c & 7;
      int pc = c16 ^ (row & 7);
      *(bf16x8*)((char*)lA + row * 128 + pc * 16) = ar[i];
      *(bf16x8*)((char*)lB + row * 128 + pc * 16) = br[i];
    }
    __syncthreads();
    if (kt + 1 < nkt) {
      int kofs = (kt + 1) << 6;
#pragma unroll
      for (int i = 0; i < 4; ++i) {
        int c = tid + i * 256, row = c >> 3, c16 = c & 7;
        ar[i] = *(const bf16x8*)(A + (size_t)(bm + row) * K + kofs + c16 * 8);
        br[i] = *(const bf16x8*)(Bt + (size_t)(bn + row) * K + kofs + c16 * 8);
      }
    }
#pragma unroll
    for (int s = 0; s < 2; ++s) {
      bf16x8 af[4], bfr[4];
#pragma unroll
      for (int f = 0; f < 4; ++f) {
        int rowa = wr * 64 + f * 16 + l16;
        int ca = (s * 4 + lhi) ^ (rowa & 7);
        af[f] = *(const bf16x8*)((char*)lA + rowa * 128 + ca * 16);
        int rowb = wc * 64 + f * 16 + l16;
        int cb = (s * 4 + lhi) ^ (rowb & 7);
        bfr[f] = *(const bf16x8*)((char*)lB + rowb * 128 + cb * 16);
      }
#pragma unroll
      for (int fi = 0; fi < 4; ++fi)
#pragma unroll
        for (int fj = 0; fj < 4; ++fj)
          acc[fi][fj] = __builtin_amdgcn_mfma_f32_16x16x32_bf16(af[fi], bfr[fj], acc[fi][fj], 0, 0, 0);
    }
  }
}

// ---- qkv fused RoPE + Q/K/V scatter epilogue (R16 proven) ----
__device__ __forceinline__ void qkv_epilogue(f32x4 (&acc)[4][4], int bm, int bn, int tid,
                                             unsigned short* __restrict__ Qr,
                                             unsigned short* __restrict__ Kr,
                                             unsigned short* __restrict__ Vt,
                                             const float* __restrict__ cosT,
                                             const float* __restrict__ sinT) {
  const int lane = tid & 63, wv = tid >> 6;
  const int wr = wv >> 1, wc = wv & 1;
  const int l16 = lane & 15, lhi = lane >> 4;
#pragma unroll
  for (int fi = 0; fi < 4; ++fi) {
    int rbase = bm + wr * 64 + fi * 16 + lhi * 4;
    int b = rbase >> 10, sbase = rbase & 1023;
#pragma unroll
    for (int fj = 0; fj < 4; ++fj) {
      int col = bn + wc * 64 + fj * 16 + l16;
      if (col < 5120) {
        int ip = (col & 127) >> 1;
        float sgn = (col & 1) ? 1.0f : -1.0f;
        unsigned short* dst;
        if (col < 4096)
          dst = Qr + ((size_t)(b * 32 + (col >> 7)) * 1024) * 128 + (col & 127);
        else
          dst = Kr + ((size_t)(b * 8 + ((col - 4096) >> 7)) * 1024) * 128 + (col & 127);
#pragma unroll
        for (int r = 0; r < 4; ++r) {
          float own = acc[fi][fj][r];
          float other = __shfl_xor(own, 1);
          int s = sbase + r;
          float c = cosT[s * 64 + ip], sn = sinT[s * 64 + ip];
          dst[(size_t)s * 128] = f2bf(own * c + sgn * other * sn);
        }
      } else {
        int kvh = (col - 5120) >> 7, d = col & 127;
        unsigned short* dst = Vt + ((size_t)(b * 8 + kvh) * 128 + d) * 1024;
#pragma unroll
        for (int r = 0; r < 4; ++r) dst[sbase + r] = f2bf(acc[fi][fj][r]);
      }
    }
  }
}

// ---- attention tile body (R16 proven: QBLK=64, T13 defer-max, T14 prefetch,
// XOR-swizzled K/V LDS) ----
__device__ __forceinline__ void attn_tile(const unsigned short* __restrict__ Qr,
                                          const unsigned short* __restrict__ Kr,
                                          const unsigned short* __restrict__ Vt,
                                          unsigned short* __restrict__ Out,
                                          int qt, int h, int b, int tid,
                                          unsigned short* __restrict__ lK,
                                          unsigned short* __restrict__ lV,
                                          unsigned short* __restrict__ lP) {
  const int lane = tid & 63, wv = tid >> 6;
  const int kvh = h >> 2;
  const int q0 = qt * 64;
  const int l16 = lane & 15, lhi = lane >> 4;

  const unsigned short* Qbase = Qr + ((size_t)(b * 32 + h) * 1024 + q0 + wv * 16 + l16) * 128;
  bf16x8 qf[4];
#pragma unroll
  for (int s = 0; s < 4; ++s) qf[s] = *(const bf16x8*)(Qbase + s * 32 + lhi * 8);

  const unsigned short* Kbase = Kr + (size_t)(b * 8 + kvh) * 1024 * 128;
  const unsigned short* Vbase = Vt + (size_t)(b * 8 + kvh) * 128 * 1024;

  f32x4 oacc[8] = {};
  float mrow[4] = {-1e30f, -1e30f, -1e30f, -1e30f};
  float lrow[4] = {0.f, 0.f, 0.f, 0.f};
  const int ntk = qt + 1;
  bf16x8 kreg[4], vreg[4];

#pragma unroll
  for (int i = 0; i < 4; ++i) {
    int c = tid + i * 256;
    int krow = c >> 4, kc = c & 15;
    kreg[i] = *(const bf16x8*)(Kbase + (size_t)krow * 128 + kc * 8);
    int vrow = c >> 3, vc = c & 7;
    vreg[i] = *(const bf16x8*)(Vbase + (size_t)vrow * 1024 + vc * 8);
  }

  for (int kt = 0; kt < ntk; ++kt) {
    const int k0 = kt * 64;
    __syncthreads();
#pragma unroll
    for (int i = 0; i < 4; ++i) {
      int c = tid + i * 256;
      int krow = c >> 4, kc = c & 15;
      *(bf16x8*)((char*)lK + krow * 256 + (kc ^ (krow & 7)) * 16) = kreg[i];
      int vrow = c >> 3, vc = c & 7;
      *(bf16x8*)((char*)lV + vrow * 128 + (vc ^ (vrow & 7)) * 16) = vreg[i];
    }
    __syncthreads();

    if (kt + 1 < ntk) {
      const int kn = (kt + 1) * 64;
#pragma unroll
      for (int i = 0; i < 4; ++i) {
        int c = tid + i * 256;
        int krow = c >> 4, kc = c & 15;
        kreg[i] = *(const bf16x8*)(Kbase + (size_t)(kn + krow) * 128 + kc * 8);
        int vrow = c >> 3, vc = c & 7;
        vreg[i] = *(const bf16x8*)(Vbase + (size_t)vrow * 1024 + kn + vc * 8);
      }
    }

    f32x4 sacc[4] = {};
#pragma unroll
    for (int kf = 0; kf < 4; ++kf) {
      int rowk = kf * 16 + l16;
#pragma unroll
      for (int s = 0; s < 4; ++s) {
        int ck = (s * 4 + lhi) ^ (rowk & 7);
        bf16x8 kfr = *(const bf16x8*)((char*)lK + rowk * 256 + ck * 16);
        sacc[kf] = __builtin_amdgcn_mfma_f32_16x16x32_bf16(qf[s], kfr, sacc[kf], 0, 0, 0);
      }
    }

    const int qg = q0 + wv * 16 + lhi * 4;
    float mt[4] = {-1e30f, -1e30f, -1e30f, -1e30f};
#pragma unroll
    for (int kf = 0; kf < 4; ++kf) {
      int kg = k0 + kf * 16 + l16;
#pragma unroll
      for (int r = 0; r < 4; ++r) {
        float v = sacc[kf][r] * 0.08838834764831845f;
        v = (kg <= qg + r) ? v : -1e9f;
        sacc[kf][r] = v;
        mt[r] = fmaxf(mt[r], v);
      }
    }
#pragma unroll
    for (int r = 0; r < 4; ++r) {
#pragma unroll
      for (int off = 1; off < 16; off <<= 1) mt[r] = fmaxf(mt[r], __shfl_xor(mt[r], off));
    }

    bool need = false;
#pragma unroll
    for (int r = 0; r < 4; ++r) need = need || (mt[r] > mrow[r] + 8.0f);
    const bool doresc = (__ballot(need) != 0ull);

    float alpha[4], rs[4];
#pragma unroll
    for (int r = 0; r < 4; ++r) {
      if (doresc) {
        float mn = fmaxf(mrow[r], mt[r]);
        alpha[r] = __expf(mrow[r] - mn);
        mrow[r] = mn;
      } else {
        alpha[r] = 1.0f;
      }
      rs[r] = 0.f;
    }
#pragma unroll
    for (int kf = 0; kf < 4; ++kf) {
      int key = kf * 16 + l16;
#pragma unroll
      for (int r = 0; r < 4; ++r) {
        float p = __expf(sacc[kf][r] - mrow[r]);
        rs[r] += p;
        int prow = lhi * 4 + r;
        int addr = wv * 2048 + ((prow * 128 + key * 2) ^ ((prow & 7) << 4));
        *(unsigned short*)((char*)lP + addr) = f2bf(p);
      }
    }
#pragma unroll
    for (int r = 0; r < 4; ++r) {
#pragma unroll
      for (int off = 1; off < 16; off <<= 1) rs[r] += __shfl_xor(rs[r], off);
      lrow[r] = lrow[r] * alpha[r] + rs[r];
    }
    if (doresc) {
#pragma unroll
      for (int nf = 0; nf < 8; ++nf)
#pragma unroll
        for (int r = 0; r < 4; ++r) oacc[nf][r] *= alpha[r];
    }

#pragma unroll
    for (int s2 = 0; s2 < 2; ++s2) {
      int prow = l16;
      int paddr = wv * 2048 + ((prow * 128 + s2 * 64 + lhi * 16) ^ ((prow & 7) << 4));
      bf16x8 pa = *(const bf16x8*)((char*)lP + paddr);
#pragma unroll
      for (int nf = 0; nf < 8; ++nf) {
        int rowd = nf * 16 + l16;
        int cv = (s2 * 4 + lhi) ^ (rowd & 7);
        bf16x8 vfr = *(const bf16x8*)((char*)lV + rowd * 128 + cv * 16);
        oacc[nf] = __builtin_amdgcn_mfma_f32_16x16x32_bf16(pa, vfr, oacc[nf], 0, 0, 0);
      }
    }
  }

  unsigned short* Ob = Out + ((size_t)(b * 1024) + q0 + wv * 16 + lhi * 4) * 4096 + h * 128;
#pragma unroll
  for (int r = 0; r < 4; ++r) {
    float inv = 1.f / lrow[r];
#pragma unroll
    for (int nf = 0; nf < 8; ++nf)
      Ob[(size_t)r * 4096 + nf * 16 + l16] = f2bf(oacc[nf][r] * inv);
  }
}

// ================= persistent mega-kernel: 768 blocks (3/CU), 3 grid syncs ====
// LDS 40960 x 3 = 120KB/CU (headroom vs R17's exact-160KB rejection).
// phase0: x convert + wqkv transpose (grid-stride). phase1: qkv 768 tiles 1:1.
// phase2: attn 1024 tiles — blocks<256 take complementary pairs (qt=a & 15-a);
//         blocks 256..767 take 1 tile + deficit-matched slice of w_o transposes.
// phase3: out-proj 512 tiles.
__global__ __launch_bounds__(256, 3) void k_mega(
    const float* __restrict__ x, const float* __restrict__ w_qkv,
    const float* __restrict__ w_o, const float* __restrict__ cosT,
    const float* __restrict__ sinT, unsigned short* __restrict__ xb,
    unsigned short* __restrict__ wqkv_t, unsigned short* __restrict__ wo_t,
    unsigned short* __restrict__ Qr, unsigned short* __restrict__ Kr,
    unsigned short* __restrict__ Vt, unsigned short* __restrict__ attnO,
    float* __restrict__ outp) {
  __shared__ __align__(16) char smem[40960];
  cg::grid_group grid = cg::this_grid();
  const int bid = blockIdx.x, tid = threadIdx.x;

  // phase 0: prep
  for (int it = bid; it < 14336; it += 768) {
    if (it < 8192) {
      int i = it * 256 + tid;
      float4 v = ((const float4*)x)[i];
      ushort4 o;
      o.x = f2bf(v.x); o.y = f2bf(v.y); o.z = f2bf(v.z); o.w = f2bf(v.w);
      ((ushort4*)xb)[i] = o;
    } else {
      int t = it - 8192;
      __syncthreads();
      transpose_tile(w_qkv, wqkv_t, 4096, 6144, (t % 96) * 64, (t / 96) * 64, tid, (float*)smem);
    }
  }
  __threadfence();
  grid.sync();

  // phase 1: qkv GEMM (768 tiles, 1:1)
  {
    unsigned short* lA = (unsigned short*)smem;
    unsigned short* lB = (unsigned short*)(smem + 16384);
    const int swz = (bid & 7) * 96 + (bid >> 3);
    const int bm = (swz & 15) * 128, bn = (swz >> 4) * 128;
    f32x4 acc[4][4] = {};
    gemm_core(xb, wqkv_t, 4096, bm, bn, tid, lA, lB, acc);
    qkv_epilogue(acc, bm, bn, tid, Qr, Kr, Vt, cosT, sinT);
  }
  __threadfence();
  grid.sync();

  // phase 2: attention + w_o transpose backfill
  {
    unsigned short* lK = (unsigned short*)smem;
    unsigned short* lV = (unsigned short*)(smem + 16384);
    unsigned short* lP = (unsigned short*)(smem + 32768);
    int t1 = bid; // tile: qt = t&15, h = (t>>4)&31, b = t>>9
    attn_tile(Qr, Kr, Vt, attnO, t1 & 15, (t1 >> 4) & 31, t1 >> 9, tid, lK, lV, lP);
    if (bid < 256) {
      int t2 = 1023 - bid; // complementary causal weight
      attn_tile(Qr, Kr, Vt, attnO, t2 & 15, (t2 >> 4) & 31, t2 >> 9, tid, lK, lV, lP);
    } else {
      // deficit-matched w_o transposes: block (g = (bid-256)>>4, a = bid&15)
      // gets 16-a tiles starting at g*136 + 16a - a(a-1)/2 (bijective onto [0,4352); clamp 4096)
      int g = (bid - 256) >> 4, a = bid & 15;
      int t0 = g * 136 + 16 * a - (a * (a - 1)) / 2;
      int cnt = 16 - a;
      for (int j = 0; j < cnt; ++j) {
        int t = t0 + j;
        if (t < 4096) {
          __syncthreads();
          transpose_tile(w_o, wo_t, 4096, 4096, (t & 63) * 64, (t >> 6) * 64, tid, (float*)smem);
        }
      }
    }
  }
  __threadfence();
  grid.sync();

  // phase 3: out-proj GEMM (512 tiles)
  if (bid < 512) {
    unsigned short* lA = (unsigned short*)smem;
    unsigned short* lB = (unsigned short*)(smem + 16384);
    const int swz = (bid & 7) * 64 + (bid >> 3);
    const int bm = (swz & 15) * 128, bn = (swz >> 4) * 128;
    f32x4 acc[4][4] = {};
    gemm_core(attnO, wo_t, 4096, bm, bn, tid, lA, lB, acc);
    const int lane = tid & 63, wv = tid >> 6;
    const int wr = wv >> 1, wc = wv & 1;
    const int l16 = lane & 15, lhi = lane >> 4;
#pragma unroll
    for (int fi = 0; fi < 4; ++fi) {
      int rbase = bm + wr * 64 + fi * 16 + lhi * 4;
#pragma unroll
      for (int fj = 0; fj < 4; ++fj) {
        int col = bn + wc * 64 + fj * 16 + l16;
#pragma unroll
        for (int r = 0; r < 4; ++r)
          outp[(size_t)(rbase + r) * 4096 + col] = acc[fi][fj][r];
      }
    }
  }
}

// ================= fallback path (R16 proven, 318.8us) =================
__global__ __launch_bounds__(256) void k_prep(const float* __restrict__ x,
                                              const float* __restrict__ w_qkv,
                                              unsigned short* __restrict__ xb,
                                              unsigned short* __restrict__ wqkv_t) {
  __shared__ float tb[64 * 65];
  const int bid = blockIdx.x, tid = threadIdx.x;
  if (bid < 8192) {
    int i = bid * 256 + tid;
    float4 v = ((const float4*)x)[i];
    ushort4 o;
    o.x = f2bf(v.x); o.y = f2bf(v.y); o.z = f2bf(v.z); o.w = f2bf(v.w);
    ((ushort4*)xb)[i] = o;
  } else {
    int t = bid - 8192;
    transpose_tile(w_qkv, wqkv_t, 4096, 6144, (t % 96) * 64, (t / 96) * 64, tid, tb);
  }
}

__global__ __launch_bounds__(256) void k_qkv(const unsigned short* __restrict__ A,
                                             const unsigned short* __restrict__ Bt,
                                             unsigned short* __restrict__ Qr,
                                             unsigned short* __restrict__ Kr,
                                             unsigned short* __restrict__ Vt,
                                             const float* __restrict__ cosT,
                                             const float* __restrict__ sinT,
                                             const float* __restrict__ w_o,
                                             unsigned short* __restrict__ wo_t) {
  __shared__ __align__(16) char smem[32768];
  const int bid = blockIdx.x, tid = threadIdx.x;
  if (bid >= 768) {
    int t = bid - 768;
    transpose_tile(w_o, wo_t, 4096, 4096, (t & 63) * 64, (t >> 6) * 64, tid, (float*)smem);
    return;
  }
  unsigned short* lA = (unsigned short*)smem;
  unsigned short* lB = (unsigned short*)(smem + 16384);
  const int swz = (bid & 7) * 96 + (bid >> 3);
  const int bm = (swz & 15) * 128, bn = (swz >> 4) * 128;
  f32x4 acc[4][4] = {};
  gemm_core(A, Bt, 4096, bm, bn, tid, lA, lB, acc);
  qkv_epilogue(acc, bm, bn, tid, Qr, Kr, Vt, cosT, sinT);
}

__global__ __launch_bounds__(256) void k_attn(const unsigned short* __restrict__ Qr,
                                              const unsigned short* __restrict__ Kr,
                                              const unsigned short* __restrict__ Vt,
                                              unsigned short* __restrict__ Out) {
  __shared__ __align__(16) char smem[40960];
  unsigned short* lK = (unsigned short*)smem;
  unsigned short* lV = (unsigned short*)(smem + 16384);
  unsigned short* lP = (unsigned short*)(smem + 32768);
  const int qt = (int)gridDim.x - 1 - (int)blockIdx.x;
  attn_tile(Qr, Kr, Vt, Out, qt, blockIdx.y, blockIdx.z, threadIdx.x, lK, lV, lP);
}

__global__ __launch_bounds__(256) void k_out(const unsigned short* __restrict__ A,
                                             const unsigned short* __restrict__ Bt,
                                             float* __restrict__ C) {
  __shared__ __align__(16) char smem[32768];
  unsigned short* lA = (unsigned short*)smem;
  unsigned short* lB = (unsigned short*)(smem + 16384);
  const int tid = threadIdx.x;
  const int lid = blockIdx.y * gridDim.x + blockIdx.x;
  const int swz = (lid & 7) * 64 + (lid >> 3);
  const int bm = (swz & 15) * 128, bn = (swz >> 4) * 128;
  f32x4 acc[4][4] = {};
  gemm_core(A, Bt, 4096, bm, bn, tid, lA, lB, acc);
  const int lane = tid & 63, wv = tid >> 6;
  const int wr = wv >> 1, wc = wv & 1;
  const int l16 = lane & 15, lhi = lane >> 4;
#pragma unroll
  for (int fi = 0; fi < 4; ++fi) {
    int rbase = bm + wr * 64 + fi * 16 + lhi * 4;
#pragma unroll
    for (int fj = 0; fj < 4; ++fj) {
      int col = bn + wc * 64 + fj * 16 + l16;
#pragma unroll
      for (int r = 0; r < 4; ++r)
        C[(size_t)(rbase + r) * 4096 + col] = acc[fi][fj][r];
    }
  }
}

extern "C" void kernel_launch(void* const* d_in, const int* in_sizes, int n_in,
                              void* d_out, int out_size, void* d_ws, size_t ws_size,
                              hipStream_t stream) {
  const float* x = (const float*)d_in[0];
  const float* w_qkv = (const float*)d_in[1];
  const float* w_o = (const float*)d_in[2];
  const float* cosT = (const float*)d_in[3];
  const float* sinT = (const float*)d_in[4];

  char* ws = (char*)d_ws;
  unsigned short* wqkv_t = (unsigned short*)(ws);                 // 6144x4096 bf16
  unsigned short* wo_t   = (unsigned short*)(ws + 50331648);      // 4096x4096 bf16
  unsigned short* xb     = (unsigned short*)(ws + 83886080);      // 2048x4096 bf16
  unsigned short* Qr     = (unsigned short*)(ws + 100663296);     // 2*32*1024*128 bf16
  unsigned short* Kr     = (unsigned short*)(ws + 117440512);     // 2*8*1024*128 bf16
  unsigned short* Vt     = (unsigned short*)(ws + 121634816);     // 2*8*128*1024 bf16
  unsigned short* attn   = (unsigned short*)(ws + 125829120);     // 2048x4096 bf16
  float* outp = (float*)d_out;

  // Deterministic host-side guard: same device -> same answer every call.
  int dev = 0;
  hipGetDevice(&dev);
  hipDeviceProp_t prop;
  hipGetDeviceProperties(&prop, dev);
  int nb = 0;
  hipOccupancyMaxActiveBlocksPerMultiprocessor(&nb, k_mega, 256, 0);
  bool coop = (prop.cooperativeLaunch != 0) && (nb * prop.multiProcessorCount >= 768);

  if (coop) {
    void* args[] = {&x, &w_qkv, &w_o, &cosT, &sinT, &xb, &wqkv_t, &wo_t,
                    &Qr, &Kr, &Vt, &attn, &outp};
    hipError_t e = hipLaunchCooperativeKernel((const void*)k_mega, dim3(768), dim3(256),
                                              args, 0, stream);
    if (e == hipSuccess) return;
  }

  // fallback: proven 4-dispatch path (R16)
  k_prep<<<14336, 256, 0, stream>>>(x, w_qkv, xb, wqkv_t);
  k_qkv<<<768 + 4096, 256, 0, stream>>>(xb, wqkv_t, Qr, Kr, Vt, cosT, sinT, w_o, wo_t);
  k_attn<<<dim3(16, 32, 2), 256, 0, stream>>>(Qr, Kr, Vt, attn);
  k_out<<<dim3(16, 32), 256, 0, stream>>>(attn, wo_t, outp);
}

// Round 19
// 318.001 us; speedup vs baseline: 1.0851x; 1.0851x over previous
//
#include <hip/hip_runtime.h>
#include <cstdint>
#include <cstddef>

// B=2 S=1024 H=4096 NH=32 NKV=8 HD=128 GROUPS=4
typedef short bf16x8 __attribute__((ext_vector_type(8)));
typedef float f32x4 __attribute__((ext_vector_type(4)));

__device__ __forceinline__ unsigned short f2bf(float f) {
  unsigned int u = __builtin_bit_cast(unsigned int, f);
  u += 0x7fffu + ((u >> 16) & 1u);
  return (unsigned short)(u >> 16);
}

// ---- transpose tile core: 64x64, float4 loads / bf16x8 stores; caller-provided LDS ----
__device__ __forceinline__ void transpose_tile(const float* __restrict__ src,
                                               unsigned short* __restrict__ dst,
                                               int K, int N, int n0, int k0, int tid,
                                               float* __restrict__ tb /* [64][65] */) {
#pragma unroll
  for (int i = 0; i < 4; ++i) {
    const int lr = tid >> 4, lc = (tid & 15) * 4;
    float4 v = *(const float4*)(src + (size_t)(k0 + i * 16 + lr) * N + n0 + lc);
    tb[(i * 16 + lr) * 65 + lc] = v.x;
    tb[(i * 16 + lr) * 65 + lc + 1] = v.y;
    tb[(i * 16 + lr) * 65 + lc + 2] = v.z;
    tb[(i * 16 + lr) * 65 + lc + 3] = v.w;
  }
  __syncthreads();
  const int nr = tid >> 3, kk = (tid & 7) * 8;
#pragma unroll
  for (int i = 0; i < 2; ++i) {
    int n = nr + i * 32;
    bf16x8 v;
#pragma unroll
    for (int j = 0; j < 8; ++j) v[j] = (short)f2bf(tb[(kk + j) * 65 + n]);
    *(bf16x8*)(dst + (size_t)(n0 + n) * K + k0 + kk) = v;
  }
}

// ---- prep: x convert (blocks [0,8192)) + w_qkv transpose [8192,14336) ----
__global__ __launch_bounds__(256) void k_prep(const float* __restrict__ x,
                                              const float* __restrict__ w_qkv,
                                              unsigned short* __restrict__ xb,
                                              unsigned short* __restrict__ wqkv_t) {
  __shared__ float tb[64 * 65];
  const int bid = blockIdx.x, tid = threadIdx.x;
  if (bid < 8192) {
    int i = bid * 256 + tid;
    float4 v = ((const float4*)x)[i];
    ushort4 o;
    o.x = f2bf(v.x); o.y = f2bf(v.y); o.z = f2bf(v.z); o.w = f2bf(v.w);
    ((ushort4*)xb)[i] = o;
  } else {
    int t = bid - 8192;
    transpose_tile(w_qkv, wqkv_t, 4096, 6144, (t % 96) * 64, (t / 96) * 64, tid, tb);
  }
}

// ---- GEMM (R11 proven: depth-1 reg-staged, VGPR 80): BM=BN=128, BK=64, 4 waves,
// XOR-swizzled ds_write, prefetch after barrier, T1 XCD swizzle.
// MODE 0: 2D grid, C[M,N] f32 out.
// MODE 1: 1D grid; bid<768 = qkv-proj tile (fused RoPE + Q/K/V scatter epilogue);
//         bid>=768 = one 64x64 w_o transpose tile, co-scheduled into the idle
//         LDS/wave/BW slots of the GEMM's 3-blocks/CU steady state (LDS overlaid
//         in the same 32KB footprint so GEMM occupancy is untouched).
template <int MODE>
__global__ __launch_bounds__(256) void k_gemm(const unsigned short* __restrict__ A,
                                              const unsigned short* __restrict__ Bt,
                                              float* __restrict__ C,
                                              unsigned short* __restrict__ Qr,
                                              unsigned short* __restrict__ Kr,
                                              unsigned short* __restrict__ Vt,
                                              const float* __restrict__ cosT,
                                              const float* __restrict__ sinT,
                                              const float* __restrict__ w_o,
                                              unsigned short* __restrict__ wo_t,
                                              int M, int N, int K) {
  __shared__ __align__(16) char smem[32768]; // GEMM: lA|lB ; transpose: 64x65 f32
  unsigned short* lA = (unsigned short*)smem;
  unsigned short* lB = (unsigned short*)(smem + 16384);
  const int tid = threadIdx.x;

  int bm, bn;
  if (MODE == 1) {
    const int bid = blockIdx.x;
    if (bid >= 768) { // w_o transpose backfill
      int t = bid - 768;
      transpose_tile(w_o, wo_t, 4096, 4096, (t & 63) * 64, (t >> 6) * 64, tid, (float*)smem);
      return;
    }
    const int swz = (bid & 7) * 96 + (bid >> 3); // T1: 768 tiles, 16 bm x 48 bn
    bm = (swz & 15) * 128;
    bn = (swz >> 4) * 128;
  } else {
    const int lid = blockIdx.y * gridDim.x + blockIdx.x;
    const int cpx = (gridDim.x * gridDim.y) >> 3;
    const int swz = (lid & 7) * cpx + (lid >> 3);
    bm = (swz % gridDim.x) * 128;
    bn = (swz / gridDim.x) * 128;
  }

  const int lane = tid & 63, wv = tid >> 6;
  const int wr = wv >> 1, wc = wv & 1;
  const int l16 = lane & 15, lhi = lane >> 4;
  f32x4 acc[4][4] = {};
  bf16x8 ar[4], br[4];

#pragma unroll
  for (int i = 0; i < 4; ++i) {
    int c = tid + i * 256, row = c >> 3, c16 = c & 7;
    ar[i] = *(const bf16x8*)(A + (size_t)(bm + row) * K + 0 + c16 * 8);
    br[i] = *(const bf16x8*)(Bt + (size_t)(bn + row) * K + 0 + c16 * 8);
  }
  const int nkt = K >> 6;
  for (int kt = 0; kt < nkt; ++kt) {
    __syncthreads();
#pragma unroll
    for (int i = 0; i < 4; ++i) {
      int c = tid + i * 256, row = c >> 3, c16 = c & 7;
      int pc = c16 ^ (row & 7);
      *(bf16x8*)((char*)lA + row * 128 + pc * 16) = ar[i];
      *(bf16x8*)((char*)lB + row * 128 + pc * 16) = br[i];
    }
    __syncthreads();
    if (kt + 1 < nkt) {
      int kofs = (kt + 1) << 6;
#pragma unroll
      for (int i = 0; i < 4; ++i) {
        int c = tid + i * 256, row = c >> 3, c16 = c & 7;
        ar[i] = *(const bf16x8*)(A + (size_t)(bm + row) * K + kofs + c16 * 8);
        br[i] = *(const bf16x8*)(Bt + (size_t)(bn + row) * K + kofs + c16 * 8);
      }
    }
#pragma unroll
    for (int s = 0; s < 2; ++s) {
      bf16x8 af[4], bfr[4];
#pragma unroll
      for (int f = 0; f < 4; ++f) {
        int rowa = wr * 64 + f * 16 + l16;
        int ca = (s * 4 + lhi) ^ (rowa & 7);
        af[f] = *(const bf16x8*)((char*)lA + rowa * 128 + ca * 16);
        int rowb = wc * 64 + f * 16 + l16;
        int cb = (s * 4 + lhi) ^ (rowb & 7);
        bfr[f] = *(const bf16x8*)((char*)lB + rowb * 128 + cb * 16);
      }
#pragma unroll
      for (int fi = 0; fi < 4; ++fi)
#pragma unroll
        for (int fj = 0; fj < 4; ++fj)
          acc[fi][fj] = __builtin_amdgcn_mfma_f32_16x16x32_bf16(af[fi], bfr[fj], acc[fi][fj], 0, 0, 0);
    }
  }

  if (MODE == 0) {
#pragma unroll
    for (int fi = 0; fi < 4; ++fi) {
      int rbase = bm + wr * 64 + fi * 16 + lhi * 4;
#pragma unroll
      for (int fj = 0; fj < 4; ++fj) {
        int col = bn + wc * 64 + fj * 16 + l16;
#pragma unroll
        for (int r = 0; r < 4; ++r)
          C[(size_t)(rbase + r) * N + col] = acc[fi][fj][r];
      }
    }
  } else {
    // qkv: cols [0,4096)=Q rope, [4096,5120)=K rope, [5120,6144)=V transpose.
#pragma unroll
    for (int fi = 0; fi < 4; ++fi) {
      int rbase = bm + wr * 64 + fi * 16 + lhi * 4;
      int b = rbase >> 10, sbase = rbase & 1023;
#pragma unroll
      for (int fj = 0; fj < 4; ++fj) {
        int col = bn + wc * 64 + fj * 16 + l16;
        if (col < 5120) {
          int i = (col & 127) >> 1;
          float sgn = (col & 1) ? 1.0f : -1.0f;
          unsigned short* dst;
          if (col < 4096)
            dst = Qr + ((size_t)(b * 32 + (col >> 7)) * 1024) * 128 + (col & 127);
          else
            dst = Kr + ((size_t)(b * 8 + ((col - 4096) >> 7)) * 1024) * 128 + (col & 127);
#pragma unroll
          for (int r = 0; r < 4; ++r) {
            float own = acc[fi][fj][r];
            float other = __shfl_xor(own, 1);
            int s = sbase + r;
            float c = cosT[s * 64 + i], sn = sinT[s * 64 + i];
            dst[(size_t)s * 128] = f2bf(own * c + sgn * other * sn);
          }
        } else {
          int kvh = (col - 5120) >> 7, d = col & 127;
          unsigned short* dst = Vt + ((size_t)(b * 8 + kvh) * 128 + d) * 1024;
#pragma unroll
          for (int r = 0; r < 4; ++r) dst[sbase + r] = f2bf(acc[fi][fj][r]);
        }
      }
    }
  }
}

// ---- flash attention (R13 proven): QBLK=64, 4 waves, LPT qt order, T13 defer-max,
// T14 post-barrier prefetch, XOR-swizzled K/V LDS ----
__global__ __launch_bounds__(256) void k_attn(const unsigned short* __restrict__ Qr,
                                              const unsigned short* __restrict__ Kr,
                                              const unsigned short* __restrict__ Vt,
                                              unsigned short* __restrict__ Out) {
  __shared__ __align__(16) unsigned short lK[64 * 128];
  __shared__ __align__(16) unsigned short lV[128 * 64];
  __shared__ __align__(16) unsigned short lP[4 * 16 * 64];
  const int tid = threadIdx.x, lane = tid & 63, wv = tid >> 6;
  const int qt = (int)gridDim.x - 1 - (int)blockIdx.x; // LPT: heavy blocks first
  const int h = blockIdx.y, b = blockIdx.z;
  const int kvh = h >> 2;
  const int q0 = qt * 64;
  const int l16 = lane & 15, lhi = lane >> 4;

  const unsigned short* Qbase = Qr + ((size_t)(b * 32 + h) * 1024 + q0 + wv * 16 + l16) * 128;
  bf16x8 qf[4];
#pragma unroll
  for (int s = 0; s < 4; ++s) qf[s] = *(const bf16x8*)(Qbase + s * 32 + lhi * 8);

  const unsigned short* Kbase = Kr + (size_t)(b * 8 + kvh) * 1024 * 128;
  const unsigned short* Vbase = Vt + (size_t)(b * 8 + kvh) * 128 * 1024;

  f32x4 oacc[8] = {};
  float mrow[4] = {-1e30f, -1e30f, -1e30f, -1e30f};
  float lrow[4] = {0.f, 0.f, 0.f, 0.f};
  const int ntk = qt + 1;
  bf16x8 kreg[4], vreg[4];

#pragma unroll
  for (int i = 0; i < 4; ++i) {
    int c = tid + i * 256;
    int krow = c >> 4, kc = c & 15;
    kreg[i] = *(const bf16x8*)(Kbase + (size_t)krow * 128 + kc * 8);
    int vrow = c >> 3, vc = c & 7;
    vreg[i] = *(const bf16x8*)(Vbase + (size_t)vrow * 1024 + vc * 8);
  }

  for (int kt = 0; kt < ntk; ++kt) {
    const int k0 = kt * 64;
    __syncthreads();
#pragma unroll
    for (int i = 0; i < 4; ++i) {
      int c = tid + i * 256;
      int krow = c >> 4, kc = c & 15;
      *(bf16x8*)((char*)lK + krow * 256 + (kc ^ (krow & 7)) * 16) = kreg[i];
      int vrow = c >> 3, vc = c & 7;
      *(bf16x8*)((char*)lV + vrow * 128 + (vc ^ (vrow & 7)) * 16) = vreg[i];
    }
    __syncthreads();

    if (kt + 1 < ntk) {
      const int kn = (kt + 1) * 64;
#pragma unroll
      for (int i = 0; i < 4; ++i) {
        int c = tid + i * 256;
        int krow = c >> 4, kc = c & 15;
        kreg[i] = *(const bf16x8*)(Kbase + (size_t)(kn + krow) * 128 + kc * 8);
        int vrow = c >> 3, vc = c & 7;
        vreg[i] = *(const bf16x8*)(Vbase + (size_t)vrow * 1024 + kn + vc * 8);
      }
    }

    f32x4 sacc[4] = {};
#pragma unroll
    for (int kf = 0; kf < 4; ++kf) {
      int rowk = kf * 16 + l16;
#pragma unroll
      for (int s = 0; s < 4; ++s) {
        int ck = (s * 4 + lhi) ^ (rowk & 7);
        bf16x8 kfr = *(const bf16x8*)((char*)lK + rowk * 256 + ck * 16);
        sacc[kf] = __builtin_amdgcn_mfma_f32_16x16x32_bf16(qf[s], kfr, sacc[kf], 0, 0, 0);
      }
    }

    const int qg = q0 + wv * 16 + lhi * 4;
    float mt[4] = {-1e30f, -1e30f, -1e30f, -1e30f};
#pragma unroll
    for (int kf = 0; kf < 4; ++kf) {
      int kg = k0 + kf * 16 + l16;
#pragma unroll
      for (int r = 0; r < 4; ++r) {
        float v = sacc[kf][r] * 0.08838834764831845f;
        v = (kg <= qg + r) ? v : -1e9f;
        sacc[kf][r] = v;
        mt[r] = fmaxf(mt[r], v);
      }
    }
#pragma unroll
    for (int r = 0; r < 4; ++r) {
#pragma unroll
      for (int off = 1; off < 16; off <<= 1) mt[r] = fmaxf(mt[r], __shfl_xor(mt[r], off));
    }

    bool need = false;
#pragma unroll
    for (int r = 0; r < 4; ++r) need = need || (mt[r] > mrow[r] + 8.0f);
    const bool doresc = (__ballot(need) != 0ull);

    float alpha[4], rs[4];
#pragma unroll
    for (int r = 0; r < 4; ++r) {
      if (doresc) {
        float mn = fmaxf(mrow[r], mt[r]);
        alpha[r] = __expf(mrow[r] - mn);
        mrow[r] = mn;
      } else {
        alpha[r] = 1.0f;
      }
      rs[r] = 0.f;
    }
#pragma unroll
    for (int kf = 0; kf < 4; ++kf) {
      int key = kf * 16 + l16;
#pragma unroll
      for (int r = 0; r < 4; ++r) {
        float p = __expf(sacc[kf][r] - mrow[r]);
        rs[r] += p;
        int prow = lhi * 4 + r;
        int addr = wv * 2048 + ((prow * 128 + key * 2) ^ ((prow & 7) << 4));
        *(unsigned short*)((char*)lP + addr) = f2bf(p);
      }
    }
#pragma unroll
    for (int r = 0; r < 4; ++r) {
#pragma unroll
      for (int off = 1; off < 16; off <<= 1) rs[r] += __shfl_xor(rs[r], off);
      lrow[r] = lrow[r] * alpha[r] + rs[r];
    }
    if (doresc) {
#pragma unroll
      for (int nf = 0; nf < 8; ++nf)
#pragma unroll
        for (int r = 0; r < 4; ++r) oacc[nf][r] *= alpha[r];
    }

#pragma unroll
    for (int s2 = 0; s2 < 2; ++s2) {
      int prow = l16;
      int paddr = wv * 2048 + ((prow * 128 + s2 * 64 + lhi * 16) ^ ((prow & 7) << 4));
      bf16x8 pa = *(const bf16x8*)((char*)lP + paddr);
#pragma unroll
      for (int nf = 0; nf < 8; ++nf) {
        int rowd = nf * 16 + l16;
        int cv = (s2 * 4 + lhi) ^ (rowd & 7);
        bf16x8 vfr = *(const bf16x8*)((char*)lV + rowd * 128 + cv * 16);
        oacc[nf] = __builtin_amdgcn_mfma_f32_16x16x32_bf16(pa, vfr, oacc[nf], 0, 0, 0);
      }
    }
  }

  unsigned short* Ob = Out + ((size_t)(b * 1024) + q0 + wv * 16 + lhi * 4) * 4096 + h * 128;
#pragma unroll
  for (int r = 0; r < 4; ++r) {
    float inv = 1.f / lrow[r];
#pragma unroll
    for (int nf = 0; nf < 8; ++nf)
      Ob[(size_t)r * 4096 + nf * 16 + l16] = f2bf(oacc[nf][r] * inv);
  }
}

extern "C" void kernel_launch(void* const* d_in, const int* in_sizes, int n_in,
                              void* d_out, int out_size, void* d_ws, size_t ws_size,
                              hipStream_t stream) {
  const float* x = (const float*)d_in[0];
  const float* w_qkv = (const float*)d_in[1];
  const float* w_o = (const float*)d_in[2];
  const float* cosT = (const float*)d_in[3];
  const float* sinT = (const float*)d_in[4];

  char* ws = (char*)d_ws;
  unsigned short* wqkv_t = (unsigned short*)(ws);                 // 6144x4096 bf16
  unsigned short* wo_t   = (unsigned short*)(ws + 50331648);      // 4096x4096 bf16
  unsigned short* xb     = (unsigned short*)(ws + 83886080);      // 2048x4096 bf16
  unsigned short* Qr     = (unsigned short*)(ws + 100663296);     // 2*32*1024*128 bf16
  unsigned short* Kr     = (unsigned short*)(ws + 117440512);     // 2*8*1024*128 bf16
  unsigned short* Vt     = (unsigned short*)(ws + 121634816);     // 2*8*128*1024 bf16
  unsigned short* attn   = (unsigned short*)(ws + 125829120);     // 2048x4096 bf16

  k_prep<<<14336, 256, 0, stream>>>(x, w_qkv, xb, wqkv_t);
  k_gemm<1><<<768 + 4096, 256, 0, stream>>>(xb, wqkv_t, nullptr, Qr, Kr, Vt, cosT, sinT,
                                            w_o, wo_t, 2048, 6144, 4096);
  k_attn<<<dim3(16, 32, 2), 256, 0, stream>>>(Qr, Kr, Vt, attn);
  k_gemm<0><<<dim3(16, 32), 256, 0, stream>>>(attn, wo_t, (float*)d_out, nullptr, nullptr, nullptr,
                                              nullptr, nullptr, nullptr, nullptr, 2048, 4096, 4096);
}